// Round 5
// baseline (232.504 us; speedup 1.0000x reference)
//
#include <hip/hip_runtime.h>

// Problem constants
#define DIMV   512
#define NEMB   4096
#define NTOK   32768                 // B*H*W
#define TOTAL  (NTOK * DIMV)        // 16,777,216

// Output layout (flat f32, concatenated in return order)
#define OFF_Q    0u
#define OFF_DIFF 16777216u
#define OFF_IND  16777217u
#define OFF_NE   16809985u
#define OFF_NCS  18907137u
#define OFF_NEA  18911233u

// ws layout (float-element offsets)
#define WS_SUMT    0u          // float [NEMB][DIMV]  (8 MB)
#define WS_BINCNT  2097152u    // int[4096]
#define WS_BINST   2101248u    // int[4096]
#define WS_SORTED  2105344u    // int[32768]
#define WS_DIFF    2138112u    // float
#define WS_NSUM    2138113u    // float

#define DECAYF 0.99f
#define OMDF   0.01f
#define EPSF   1e-5f

// ---------------------------------------------------------------------------
// Single-block fused sort: histogram + embed_ind + ncs + n_sum + scan +
// counting-sort scatter. Also zeroes diff_acc (replaces memset node).
__global__ __launch_bounds__(1024) void k_sort(
        const int*   __restrict__ labels,
        const float* __restrict__ cluster_size,
        float* __restrict__ out,
        int*   __restrict__ bin_count,
        int*   __restrict__ bin_start,
        int*   __restrict__ sorted_tok,
        float* __restrict__ n_sum,
        float* __restrict__ diff_acc) {
    __shared__ int   hist[NEMB];    // 16 KB; becomes cursor after scan
    __shared__ int   part[1024];    // 4 KB scan temp
    __shared__ float fred[1024];    // 4 KB ncs-sum reduce
    int t = threadIdx.x;
    #pragma unroll
    for (int i = 0; i < 4; ++i) hist[t + i * 1024] = 0;
    __syncthreads();

    // histogram + embed_ind (int4 loads; labels cached in registers)
    int4 labs[8];
    #pragma unroll
    for (int i = 0; i < 8; ++i) {
        int n4 = (i * 1024 + t) * 4;
        int4 l = *(const int4*)(labels + n4);
        labs[i] = l;
        out[OFF_IND + n4 + 0] = (float)l.x;
        out[OFF_IND + n4 + 1] = (float)l.y;
        out[OFF_IND + n4 + 2] = (float)l.z;
        out[OFF_IND + n4 + 3] = (float)l.w;
        atomicAdd(&hist[l.x], 1); atomicAdd(&hist[l.y], 1);
        atomicAdd(&hist[l.z], 1); atomicAdd(&hist[l.w], 1);
    }
    __syncthreads();

    // counts -> global, ncs, thread-local exclusive prefix
    int c[4]; int csum = 0; float nl = 0.f;
    #pragma unroll
    for (int i = 0; i < 4; ++i) {
        int b = t * 4 + i;
        int cc = hist[b];
        c[i] = csum; csum += cc;
        bin_count[b] = cc;
        float ncs = cluster_size[b] * DECAYF + OMDF * (float)cc;
        out[OFF_NCS + b] = ncs;
        nl += ncs;
    }
    part[t] = csum;
    fred[t] = nl;
    __syncthreads();
    // Hillis-Steele inclusive scan over 1024 thread-totals
    for (int o = 1; o < 1024; o <<= 1) {
        int v = (t >= o) ? part[t - o] : 0;
        __syncthreads();
        part[t] += v;
        __syncthreads();
    }
    // reduce ncs sum -> n_sum
    for (int o = 512; o > 0; o >>= 1) {
        if (t < o) fred[t] += fred[t + o];
        __syncthreads();
    }
    if (t == 0) { n_sum[0] = fred[0]; diff_acc[0] = 0.f; }

    int base = part[t] - csum;       // exclusive block offset
    #pragma unroll
    for (int i = 0; i < 4; ++i)
        bin_start[t * 4 + i] = base + c[i];
    __syncthreads();
    #pragma unroll
    for (int i = 0; i < 4; ++i) hist[t * 4 + i] = base + c[i];   // cursor
    __syncthreads();

    // scatter
    #pragma unroll
    for (int i = 0; i < 8; ++i) {
        int n4 = (i * 1024 + t) * 4;
        int4 l = labs[i];
        sorted_tok[atomicAdd(&hist[l.x], 1)] = n4 + 0;
        sorted_tok[atomicAdd(&hist[l.y], 1)] = n4 + 1;
        sorted_tok[atomicAdd(&hist[l.z], 1)] = n4 + 2;
        sorted_tok[atomicAdd(&hist[l.w], 1)] = n4 + 3;
    }
}

// ---------------------------------------------------------------------------
// ONE WAVE PER LABEL: fused quantize + diff + segment sum.
// 1024 blocks x 4 independent waves. Lane owns 8 dims (two float4s), so a
// wave covers the full 512-dim row; token indices broadcast via __shfl.
// No LDS, no __syncthreads in the hot path; 1-deep row prefetch.
__global__ __launch_bounds__(256) void k_perlabel(
        const float* __restrict__ inp,
        const float* __restrict__ embed,
        const int*   __restrict__ sorted_tok,
        const int*   __restrict__ bin_start,
        const int*   __restrict__ bin_count,
        float* __restrict__ out,
        float* __restrict__ sumT,
        float* __restrict__ diff_acc) {
    int t    = threadIdx.x;
    int wave = t >> 6;
    int lane = t & 63;
    int e    = (blockIdx.x << 2) | wave;   // label for this wave
    int d0   = lane << 3;                  // 8 dims per lane

    // embed column e (8 scattered scalar loads, once per wave)
    const float* col = embed + e;
    float4 qa, qb;
    qa.x = col[(size_t)(d0 + 0) * NEMB];
    qa.y = col[(size_t)(d0 + 1) * NEMB];
    qa.z = col[(size_t)(d0 + 2) * NEMB];
    qa.w = col[(size_t)(d0 + 3) * NEMB];
    qb.x = col[(size_t)(d0 + 4) * NEMB];
    qb.y = col[(size_t)(d0 + 5) * NEMB];
    qb.z = col[(size_t)(d0 + 6) * NEMB];
    qb.w = col[(size_t)(d0 + 7) * NEMB];

    int start = bin_start[e];
    int cnt   = bin_count[e];

    float4 sa = make_float4(0, 0, 0, 0);
    float4 sb = make_float4(0, 0, 0, 0);
    float dacc = 0.f;

    for (int base = 0; base < cnt; base += 64) {
        int m = min(64, cnt - base);
        // lane l holds the index of token (base + l)
        int idx = (lane < m) ? sorted_tok[start + base + lane] : 0;
        int ncur = __shfl(idx, 0);
        const float* r = inp + (size_t)ncur * DIMV + d0;
        float4 xa = *(const float4*)(r);
        float4 xb = *(const float4*)(r + 4);
        for (int i = 1; i <= m; ++i) {
            float4 pa, pb;
            int nprev = ncur;
            if (i < m) {                       // prefetch next token's row
                ncur = __shfl(idx, i);
                const float* r2 = inp + (size_t)ncur * DIMV + d0;
                pa = *(const float4*)(r2);
                pb = *(const float4*)(r2 + 4);
            }
            // accumulate current token
            sa.x += xa.x; sa.y += xa.y; sa.z += xa.z; sa.w += xa.w;
            sb.x += xb.x; sb.y += xb.y; sb.z += xb.z; sb.w += xb.w;
            float t0 = qa.x - xa.x, t1 = qa.y - xa.y, t2 = qa.z - xa.z, t3 = qa.w - xa.w;
            float u0 = qb.x - xb.x, u1 = qb.y - xb.y, u2 = qb.z - xb.z, u3 = qb.w - xb.w;
            dacc += t0 * t0 + t1 * t1 + t2 * t2 + t3 * t3
                  + u0 * u0 + u1 * u1 + u2 * u2 + u3 * u3;
            // quantize write (independent of loads)
            float* orow = out + OFF_Q + (size_t)nprev * DIMV + d0;
            *(float4*)(orow)     = qa;
            *(float4*)(orow + 4) = qb;
            if (i < m) { xa = pa; xb = pb; }
        }
    }

    // segment sum for label e (coalesced 2 KB per wave)
    float* so = sumT + (size_t)e * DIMV + d0;
    *(float4*)(so)     = sa;
    *(float4*)(so + 4) = sb;

    // diff: wave shuffle-reduce -> one atomic per wave
    for (int o = 32; o > 0; o >>= 1) dacc += __shfl_down(dacc, o);
    if (lane == 0) atomicAdd(diff_acc, dacc);
}

// ---------------------------------------------------------------------------
// Tiled transpose of sumT [e][d] + EMA + normalize + diff finalize.
__global__ __launch_bounds__(256) void k_trans_final(
        const float* __restrict__ embed_avg,
        const float* __restrict__ sumT,
        const float* __restrict__ n_sum,
        const float* __restrict__ diff_acc,
        float* __restrict__ out) {
    __shared__ float tile[32][33];
    int tx = threadIdx.x & 31;
    int ty = threadIdx.x >> 5;
    int e0 = (blockIdx.x & 127) << 5;
    int d0 = (blockIdx.x >> 7) << 5;
    for (int i = 0; i < 4; ++i) {
        int er = ty + i * 8;
        tile[er][tx] = sumT[(size_t)(e0 + er) * DIMV + d0 + tx];
    }
    __syncthreads();
    float nsum = n_sum[0];
    float ncs  = out[OFF_NCS + e0 + tx];
    float cs   = (ncs + EPSF) / (nsum + (float)NEMB * EPSF) * nsum;
    float inv  = 1.0f / cs;
    for (int i = 0; i < 4; ++i) {
        int dr = d0 + ty + i * 8;
        size_t o = (size_t)dr * NEMB + e0 + tx;
        float val = DECAYF * embed_avg[o] + OMDF * tile[tx][ty + i * 8];
        out[OFF_NEA + o] = val;
        out[OFF_NE + o]  = val * inv;
    }
    if (blockIdx.x == 0 && threadIdx.x == 0)
        out[OFF_DIFF] = diff_acc[0] * (1.0f / (float)TOTAL);
}

// ---------------------------------------------------------------------------
extern "C" void kernel_launch(void* const* d_in, const int* in_sizes, int n_in,
                              void* d_out, int out_size, void* d_ws, size_t ws_size,
                              hipStream_t stream) {
    const float* inp          = (const float*)d_in[0];
    const int*   labels       = (const int*)  d_in[1];
    const float* embed        = (const float*)d_in[2];
    const float* cluster_size = (const float*)d_in[3];
    const float* embed_avg    = (const float*)d_in[4];
    float* out = (float*)d_out;

    float* wsf        = (float*)d_ws;
    float* sumT       = wsf + WS_SUMT;
    int*   bin_count  = (int*)(wsf + WS_BINCNT);
    int*   bin_start  = (int*)(wsf + WS_BINST);
    int*   sorted_tok = (int*)(wsf + WS_SORTED);
    float* diff_acc   = wsf + WS_DIFF;
    float* n_sum      = wsf + WS_NSUM;

    k_sort      <<<1,    1024, 0, stream>>>(labels, cluster_size, out,
                                            bin_count, bin_start, sorted_tok,
                                            n_sum, diff_acc);
    k_perlabel  <<<1024, 256,  0, stream>>>(inp, embed, sorted_tok, bin_start,
                                            bin_count, out, sumT, diff_acc);
    k_trans_final<<<2048,256,  0, stream>>>(embed_avg, sumT, n_sum, diff_acc, out);
}

// Round 7
// 226.700 us; speedup vs baseline: 1.0256x; 1.0256x over previous
//
#include <hip/hip_runtime.h>

// Problem constants
#define DIMV   512
#define NEMB   4096
#define NTOK   32768                 // B*H*W
#define TOTAL  (NTOK * DIMV)         // 16,777,216

// Output layout (flat f32, concatenated in return order)
#define OFF_Q    0u
#define OFF_DIFF 16777216u
#define OFF_IND  16777217u
#define OFF_NE   16809985u
#define OFF_NCS  18907137u
#define OFF_NEA  18911233u

// ws layout (float-element offsets)
#define WS_SUMT    0u          // float [NEMB][DIMV]  (8 MB), fully overwritten
#define WS_BINCNT  2097152u    // int[4096]
#define WS_BINST   2101248u    // int[4096]
#define WS_CURSOR  2105344u    // int[4096]
#define WS_SORTED  2109440u    // int[32768]
#define WS_DIFF    2142208u    // float
#define WS_NSUM    2142209u    // float

#define DECAYF 0.99f
#define OMDF   0.01f
#define EPSF   1e-5f

// ---------------------------------------------------------------------------
// Histogram + embed_ind. 128 blocks x 256. Global atomics: 32K adds over
// 4096 lines (~8/line) -- negligible contention (proven in R2).
__global__ void k_hist(const int* __restrict__ labels,
                       float* __restrict__ out,
                       int* __restrict__ bin_count) {
    int n = blockIdx.x * 256 + threadIdx.x;
    int lab = labels[n];
    out[OFF_IND + n] = (float)lab;
    atomicAdd(&bin_count[lab], 1);
}

// ---------------------------------------------------------------------------
// Zero bin_count (runs before k_hist). 16 blocks x 256.
__global__ void k_zero(int* __restrict__ bin_count, float* __restrict__ diff_acc) {
    int i = blockIdx.x * 256 + threadIdx.x;
    bin_count[i] = 0;
    if (i == 0) diff_acc[0] = 0.f;
}

// ---------------------------------------------------------------------------
// Scan over 4096 bins + ncs + n_sum + cursor init. 1 block x 256 (tiny).
__global__ void k_scan(const int* __restrict__ bin_count,
                       const float* __restrict__ cluster_size,
                       int* __restrict__ bin_start,
                       int* __restrict__ cursor,
                       float* __restrict__ out,
                       float* __restrict__ n_sum) {
    __shared__ int   part[256];
    __shared__ float fred[256];
    int t = threadIdx.x;
    int base = t * 16;
    int loc[16];
    int s = 0; float nl = 0.f;
    #pragma unroll
    for (int i = 0; i < 16; ++i) {
        int cc = bin_count[base + i];
        loc[i] = s; s += cc;
        float ncs = cluster_size[base + i] * DECAYF + OMDF * (float)cc;
        out[OFF_NCS + base + i] = ncs;
        nl += ncs;
    }
    part[t] = s;
    fred[t] = nl;
    __syncthreads();
    for (int o = 1; o < 256; o <<= 1) {
        int v = (t >= o) ? part[t - o] : 0;
        __syncthreads();
        part[t] += v;
        __syncthreads();
    }
    for (int o = 128; o > 0; o >>= 1) {
        if (t < o) fred[t] += fred[t + o];
        __syncthreads();
    }
    if (t == 0) n_sum[0] = fred[0];
    int off = (t == 0) ? 0 : part[t - 1];
    #pragma unroll
    for (int i = 0; i < 16; ++i) {
        bin_start[base + i] = off + loc[i];
        cursor[base + i]    = off + loc[i];
    }
}

// ---------------------------------------------------------------------------
// Counting-sort scatter. 128 blocks x 256.
__global__ void k_scatter(const int* __restrict__ labels,
                          int* __restrict__ cursor,
                          int* __restrict__ sorted_tok) {
    int n = blockIdx.x * 256 + threadIdx.x;
    int lab = labels[n];
    int pos = atomicAdd(&cursor[lab], 1);
    sorted_tok[pos] = n;
}

// ---------------------------------------------------------------------------
// ONE WAVE PER LABEL, 8-deep batched load pipeline.
// 1024 blocks x 4 waves. Lane owns 8 dims; per 8-token sub-batch all 16
// float4 loads are issued before any use -> 16 KB/wave in flight.
__global__ __launch_bounds__(256) void k_perlabel(
        const float* __restrict__ inp,
        const float* __restrict__ embed,
        const int*   __restrict__ sorted_tok,
        const int*   __restrict__ bin_start,
        const int*   __restrict__ bin_count,
        float* __restrict__ out,
        float* __restrict__ sumT,
        float* __restrict__ diff_acc) {
    int t    = threadIdx.x;
    int wave = t >> 6;
    int lane = t & 63;
    int e    = (blockIdx.x << 2) | wave;   // label for this wave
    int d0   = lane << 3;                  // 8 dims per lane

    // embed column e (8 scalar stride-NEMB loads, once per wave)
    const float* col = embed + e;
    float4 qa, qb;
    qa.x = col[(size_t)(d0 + 0) * NEMB];
    qa.y = col[(size_t)(d0 + 1) * NEMB];
    qa.z = col[(size_t)(d0 + 2) * NEMB];
    qa.w = col[(size_t)(d0 + 3) * NEMB];
    qb.x = col[(size_t)(d0 + 4) * NEMB];
    qb.y = col[(size_t)(d0 + 5) * NEMB];
    qb.z = col[(size_t)(d0 + 6) * NEMB];
    qb.w = col[(size_t)(d0 + 7) * NEMB];

    int start = bin_start[e];
    int cnt   = bin_count[e];

    float4 sa = make_float4(0, 0, 0, 0);
    float4 sb = make_float4(0, 0, 0, 0);
    float dacc = 0.f;

    for (int base = 0; base < cnt; base += 64) {
        int m = min(64, cnt - base);
        int idx = (lane < m) ? sorted_tok[start + base + lane] : 0;
        for (int sub = 0; sub < m; sub += 8) {
            int mm = min(8, m - sub);
            int n[8];
            float4 xa[8], xb[8];
            // issue ALL loads for this sub-batch first (deep pipeline)
            #pragma unroll
            for (int j = 0; j < 8; ++j) {
                if (j < mm) {
                    n[j] = __shfl(idx, sub + j);
                    const float4* r =
                        (const float4*)(inp + (size_t)n[j] * DIMV + d0);
                    xa[j] = r[0];
                    xb[j] = r[1];
                }
            }
            // consume
            #pragma unroll
            for (int j = 0; j < 8; ++j) {
                if (j < mm) {
                    sa.x += xa[j].x; sa.y += xa[j].y;
                    sa.z += xa[j].z; sa.w += xa[j].w;
                    sb.x += xb[j].x; sb.y += xb[j].y;
                    sb.z += xb[j].z; sb.w += xb[j].w;
                    float t0 = qa.x - xa[j].x, t1 = qa.y - xa[j].y;
                    float t2 = qa.z - xa[j].z, t3 = qa.w - xa[j].w;
                    float u0 = qb.x - xb[j].x, u1 = qb.y - xb[j].y;
                    float u2 = qb.z - xb[j].z, u3 = qb.w - xb[j].w;
                    dacc += t0 * t0 + t1 * t1 + t2 * t2 + t3 * t3
                          + u0 * u0 + u1 * u1 + u2 * u2 + u3 * u3;
                    float4* orow =
                        (float4*)(out + OFF_Q + (size_t)n[j] * DIMV + d0);
                    orow[0] = qa;
                    orow[1] = qb;
                }
            }
        }
    }

    // segment sum for label e (coalesced 2 KB per wave; zeros if cnt==0)
    float* so = sumT + (size_t)e * DIMV + d0;
    *(float4*)(so)     = sa;
    *(float4*)(so + 4) = sb;

    // diff: wave shuffle-reduce -> one atomic per wave
    for (int o = 32; o > 0; o >>= 1) dacc += __shfl_down(dacc, o);
    if (lane == 0) atomicAdd(diff_acc, dacc);
}

// ---------------------------------------------------------------------------
// Tiled transpose of sumT [e][d] + EMA + normalize + diff finalize.
__global__ __launch_bounds__(256) void k_trans_final(
        const float* __restrict__ embed_avg,
        const float* __restrict__ sumT,
        const float* __restrict__ n_sum,
        const float* __restrict__ diff_acc,
        float* __restrict__ out) {
    __shared__ float tile[32][33];
    int tx = threadIdx.x & 31;
    int ty = threadIdx.x >> 5;
    int e0 = (blockIdx.x & 127) << 5;
    int d0 = (blockIdx.x >> 7) << 5;
    for (int i = 0; i < 4; ++i) {
        int er = ty + i * 8;
        tile[er][tx] = sumT[(size_t)(e0 + er) * DIMV + d0 + tx];
    }
    __syncthreads();
    float nsum = n_sum[0];
    float ncs  = out[OFF_NCS + e0 + tx];
    float cs   = (ncs + EPSF) / (nsum + (float)NEMB * EPSF) * nsum;
    float inv  = 1.0f / cs;
    for (int i = 0; i < 4; ++i) {
        int dr = d0 + ty + i * 8;
        size_t o = (size_t)dr * NEMB + e0 + tx;
        float val = DECAYF * embed_avg[o] + OMDF * tile[tx][ty + i * 8];
        out[OFF_NEA + o] = val;
        out[OFF_NE + o]  = val * inv;
    }
    if (blockIdx.x == 0 && threadIdx.x == 0)
        out[OFF_DIFF] = diff_acc[0] * (1.0f / (float)TOTAL);
}

// ---------------------------------------------------------------------------
extern "C" void kernel_launch(void* const* d_in, const int* in_sizes, int n_in,
                              void* d_out, int out_size, void* d_ws, size_t ws_size,
                              hipStream_t stream) {
    const float* inp          = (const float*)d_in[0];
    const int*   labels       = (const int*)  d_in[1];
    const float* embed        = (const float*)d_in[2];
    const float* cluster_size = (const float*)d_in[3];
    const float* embed_avg    = (const float*)d_in[4];
    float* out = (float*)d_out;

    float* wsf        = (float*)d_ws;
    float* sumT       = wsf + WS_SUMT;
    int*   bin_count  = (int*)(wsf + WS_BINCNT);
    int*   bin_start  = (int*)(wsf + WS_BINST);
    int*   cursor     = (int*)(wsf + WS_CURSOR);
    int*   sorted_tok = (int*)(wsf + WS_SORTED);
    float* diff_acc   = wsf + WS_DIFF;
    float* n_sum      = wsf + WS_NSUM;

    k_zero      <<<16,   256, 0, stream>>>(bin_count, diff_acc);
    k_hist      <<<128,  256, 0, stream>>>(labels, out, bin_count);
    k_scan      <<<1,    256, 0, stream>>>(bin_count, cluster_size, bin_start,
                                           cursor, out, n_sum);
    k_scatter   <<<128,  256, 0, stream>>>(labels, cursor, sorted_tok);
    k_perlabel  <<<1024, 256, 0, stream>>>(inp, embed, sorted_tok, bin_start,
                                           bin_count, out, sumT, diff_acc);
    k_trans_final<<<2048,256, 0, stream>>>(embed_avg, sumT, n_sum, diff_acc, out);
}